// Round 1
// baseline (530.260 us; speedup 1.0000x reference)
//
#include <hip/hip_runtime.h>
#include <cstdint>

// ---------------------------------------------------------------------------
// MultiHeadAttention (B=8,S=1024,D=1024,H=16,E=64). Inputs fp32, output fp32.
// Quirks: scale = 1/sqrt(8) (d_k = batch quirk); tril + exact-zero -> -1e9
// (fp32, pre-round); softmax over HEADS axis (local per (b,q,k)).
//
// R8: attention restructure for the latency-bound profile (MfmaUtil 7.7%,
// VALUBusy 30%, HBM 11%, Occ 45% -> nothing saturated, barrier/latency bound
// at 1 block/CU):
//  (1) Triangular skip: for k>q ALL heads are masked -> attn == 1/16 exactly
//      (head-axis softmax of equal values). out[q] = in-loop part (kt<=diag)
//      + (1/16)*suffix-sum(V). Suffix handled as a cheap fp32 reduction over
//      Vt (contiguous s). Halves QK^T/softmax/PV work.
//  (2) 512-thread blocks (16 q-rows, 2 heads/warp), LDS 54.3KB -> 3 blocks/CU
//      (launch_bounds(512,6)); independent barriers overlap stalls.
//  (3) 512 blocks all co-resident; pairing map qt = x<32 ? x : 95-x balances
//      the triangular work across CU slots (per-slot pair sums to ~33 iters).
// ---------------------------------------------------------------------------

typedef unsigned short u16;
typedef unsigned int   u32;
typedef __attribute__((ext_vector_type(8))) __bf16         bf16x8;
typedef __attribute__((ext_vector_type(8))) unsigned short ushort8;
typedef __attribute__((ext_vector_type(4))) float          f32x4;

#define S_ 1024
#define D_ 1024
#define H_ 16
#define E_ 64

__device__ __forceinline__ float b2f(u16 h) {
  union { u32 u; float f; } v; v.u = ((u32)h) << 16; return v.f;
}
__device__ __forceinline__ u16 f2b(float f) {      // round-to-nearest-even
  union { float f; u32 u; } v; v.f = f;
  u32 r = v.u + 0x7fffu + ((v.u >> 16) & 1u);
  return (u16)(r >> 16);
}

typedef const __attribute__((address_space(1))) u32 gu32;
typedef       __attribute__((address_space(3))) u32 lu32;

// 16B global->LDS direct load; LDS dest must be wave-uniform base + lane*16.
__device__ __forceinline__ void gload_lds16(const u16* g, u16* l) {
  __builtin_amdgcn_global_load_lds((gu32*)(uintptr_t)g, (lu32*)(uintptr_t)l,
                                   16, 0, 0);
}

// ---------------------------------------------------------------------------
// fp32 -> bf16 elementwise convert (n = multiple of 2048).
// ---------------------------------------------------------------------------
__global__ __launch_bounds__(256, 1) void cvt_bf16(
    const float* __restrict__ src, u16* __restrict__ dst)
{
  const size_t i = (size_t)blockIdx.x * 256 + threadIdx.x;
  float4 a = ((const float4*)src)[2 * i];
  float4 b = ((const float4*)src)[2 * i + 1];
  ushort8 o;
  o[0] = f2b(a.x); o[1] = f2b(a.y); o[2] = f2b(a.z); o[3] = f2b(a.w);
  o[4] = f2b(b.x); o[5] = f2b(b.y); o[6] = f2b(b.z); o[7] = f2b(b.w);
  ((ushort8*)dst)[i] = o;
}

// ---------------------------------------------------------------------------
// Weight transpose+convert: W fp32 [K][N] -> Wt bf16 [N][K]. 64x64 tiles.
// ---------------------------------------------------------------------------
__global__ __launch_bounds__(256, 1) void trans_cvt_w(
    const float* __restrict__ W, u16* __restrict__ Wt)
{
  __shared__ u16 t[64][72];
  const int k0 = blockIdx.x * 64, n0 = blockIdx.y * 64;
  const int row = threadIdx.x >> 3;
  const int cs  = (threadIdx.x & 7) * 8;
#pragma unroll
  for (int p = 0; p < 2; ++p) {
    int r = row + p * 32;
    const float* Wp = W + (size_t)(k0 + r) * 1024 + n0 + cs;
    float4 a = *(const float4*)(Wp);
    float4 b = *(const float4*)(Wp + 4);
    u16* tp = &t[r][cs];
    tp[0] = f2b(a.x); tp[1] = f2b(a.y); tp[2] = f2b(a.z); tp[3] = f2b(a.w);
    tp[4] = f2b(b.x); tp[5] = f2b(b.y); tp[6] = f2b(b.z); tp[7] = f2b(b.w);
  }
  __syncthreads();
#pragma unroll
  for (int p = 0; p < 2; ++p) {
    int n = row + p * 32;
    ushort8 v;
#pragma unroll
    for (int i = 0; i < 8; ++i) v[i] = t[cs + i][n];
    *(ushort8*)(Wt + (size_t)(n0 + n) * 1024 + k0 + cs) = v;
  }
}

// ---------------------------------------------------------------------------
// bf16 MFMA GEMM: C[M][N] = A[M][K] @ Bt[N][K]^T + bias[N] (fp32 accum).
// 128x128 tile, BK=32, 256 threads / 4 waves. m97-style global_load_lds
// width-16 staging. out_f32: 1 -> fp32 stores, 0 -> bf16 stores.
// ---------------------------------------------------------------------------
__global__ __launch_bounds__(256, 1) void gemm_bf16(
    const u16* __restrict__ A, const u16* __restrict__ Bt,
    const float* __restrict__ bias, void* __restrict__ Cv,
    int M, int N, int K, int out_f32)
{
  __shared__ u16 As[128 * 32];   // [m][k] row-major, 8KB
  __shared__ u16 Bs[128 * 32];   // [n][k] row-major, 8KB
  const int tid  = threadIdx.x;
  const int wave = tid >> 6;
  const int lane = tid & 63;
  const int quad = lane >> 4;
  const int l16  = lane & 15;
  const int m0   = (wave & 1) * 64;
  const int n0   = (wave >> 1) * 64;

  const u16* Ab = A  + (size_t)blockIdx.x * 128 * K;
  const u16* Bb = Bt + (size_t)blockIdx.y * 128 * K;

  f32x4 acc[4][4];
#pragma unroll
  for (int i = 0; i < 4; ++i)
#pragma unroll
    for (int j = 0; j < 4; ++j) acc[i][j] = (f32x4){0.f, 0.f, 0.f, 0.f};

  for (int kb = 0; kb < K; kb += 32) {
    __syncthreads();               // prior iter's LDS reads done
#pragma unroll
    for (int p = 0; p < 2; ++p) {  // 512 16B segs over 256 threads
      int seg = tid + p * 256;     // = (wave*64+p*256) + lane -> base+lane*16
      int row = seg >> 2, ks = seg & 3;
      gload_lds16(Ab + (size_t)row * K + kb + ks * 8, As + seg * 8);
      gload_lds16(Bb + (size_t)row * K + kb + ks * 8, Bs + seg * 8);
    }
    __builtin_amdgcn_s_waitcnt(0); // drain vmcnt before barrier
    __syncthreads();

    bf16x8 af[4], bfr[4];
#pragma unroll
    for (int i = 0; i < 4; ++i)    // A-frag: m=lane&15, k=quad*8+j
      af[i] = *(const bf16x8*)(As + (m0 + i * 16 + l16) * 32 + quad * 8);
#pragma unroll
    for (int j = 0; j < 4; ++j)    // B-frag: n=lane&15, k=quad*8+j
      bfr[j] = *(const bf16x8*)(Bs + (n0 + j * 16 + l16) * 32 + quad * 8);
#pragma unroll
    for (int i = 0; i < 4; ++i)
#pragma unroll
      for (int j = 0; j < 4; ++j)
        acc[i][j] = __builtin_amdgcn_mfma_f32_16x16x32_bf16(
            af[i], bfr[j], acc[i][j], 0, 0, 0);
  }

  float bv[4];
#pragma unroll
  for (int j = 0; j < 4; ++j)
    bv[j] = bias[(size_t)blockIdx.y * 128 + n0 + j * 16 + l16];

  if (out_f32) {
    float* C = (float*)Cv;
#pragma unroll
    for (int i = 0; i < 4; ++i) {
      int r = blockIdx.x * 128 + m0 + i * 16 + quad * 4;   // row=quad*4+reg
#pragma unroll
      for (int j = 0; j < 4; ++j) {
        int c = blockIdx.y * 128 + n0 + j * 16 + l16;      // col=lane&15
#pragma unroll
        for (int reg = 0; reg < 4; ++reg)
          C[(size_t)(r + reg) * N + c] = acc[i][j][reg] + bv[j];
      }
    }
  } else {
    u16* C = (u16*)Cv;
#pragma unroll
    for (int i = 0; i < 4; ++i) {
      int r = blockIdx.x * 128 + m0 + i * 16 + quad * 4;
#pragma unroll
      for (int j = 0; j < 4; ++j) {
        int c = blockIdx.y * 128 + n0 + j * 16 + l16;
#pragma unroll
        for (int reg = 0; reg < 4; ++reg)
          C[(size_t)(r + reg) * N + c] = f2b(acc[i][j][reg] + bv[j]);
      }
    }
  }
}

// ---------------------------------------------------------------------------
// V transpose (bf16): V[b][s][h*64+e] -> Vt[(b*16+h)*64+e][s]  (per-head E,S)
// ---------------------------------------------------------------------------
__global__ __launch_bounds__(256, 1) void transpose_v(
    const u16* __restrict__ V, u16* __restrict__ Vt)
{
  __shared__ u16 t[64][72];
  const int s0 = blockIdx.x * 64;
  const int bh = blockIdx.y;           // b*16 + h
  const int b = bh >> 4, h = bh & 15;
  const int row = threadIdx.x >> 3;
  const int cs  = (threadIdx.x & 7) * 8;
#pragma unroll
  for (int p = 0; p < 2; ++p) {
    int s = row + p * 32;
    *(ushort8*)(&t[s][cs]) = *(const ushort8*)(
        V + ((size_t)(b * S_ + s0 + s)) * D_ + h * E_ + cs);
  }
  __syncthreads();
#pragma unroll
  for (int p = 0; p < 2; ++p) {
    int e = row + p * 32;
    ushort8 v;
#pragma unroll
    for (int i = 0; i < 8; ++i) v[i] = t[cs + i][e];
    *(ushort8*)(Vt + ((size_t)(bh * E_ + e)) * S_ + s0 + cs) = v;
  }
}

// ---------------------------------------------------------------------------
// Fused attention, softmax over HEADS, bf16 MFMA.
// R8: triangular skip + uniform suffix term; 512 threads / 16 q-rows /
// 2 heads per warp; LDS 54.3KB -> 3 blocks/CU; balanced 1-D grid of 512.
// ---------------------------------------------------------------------------
__global__ __launch_bounds__(512, 6) void attn_headsoftmax(
    const u16* __restrict__ Qg,   // [B][S][D] bf16
    const u16* __restrict__ Kg,   // [B][S][D] bf16
    const u16* __restrict__ Vt,   // [B*H][E][S] bf16
    u16* __restrict__ AO)         // [B][S][D] bf16
{
  const int id   = blockIdx.x;         // 0..511
  const int b    = id & 7;
  const int x    = id >> 3;            // 0..63
  const int qt   = (x < 32) ? x : 95 - x;  // pair long+short per CU slot
  const int tid  = threadIdx.x;
  const int h0   = (tid >> 6) * 2;     // 2 heads per warp
  const int lane = tid & 63;
  const int quad = lane >> 4;
  const int l16  = lane & 15;
  const int q0   = qt * 16;

  __shared__ float scf[16][16][33];    // fp32 scores  (33.8 KB)
  __shared__ u16   at[16][16][40];     // bf16 attn    (20.5 KB)

  // Q fragments for both heads (row m = l16, k = quad*8+j over e-half c)
  bf16x8 qf[2][2];
#pragma unroll
  for (int hd = 0; hd < 2; ++hd) {
    const u16* Qb = Qg + ((size_t)(b * S_ + q0)) * D_ + (h0 + hd) * E_;
#pragma unroll
    for (int c = 0; c < 2; ++c)
      qf[hd][c] = *(const bf16x8*)(Qb + (size_t)l16 * D_ + c * 32 + quad * 8);
  }

  f32x4 oacc[2][4];
#pragma unroll
  for (int hd = 0; hd < 2; ++hd)
#pragma unroll
    for (int nc = 0; nc < 4; ++nc) oacc[hd][nc] = (f32x4){0.f, 0.f, 0.f, 0.f};

  // 1/sqrt(8), correctly rounded fp32; s==0 <=> dot==0 under both forms.
  const float inv_rsq8 = 0.35355339059327373f;

  const int ktEnd = (q0 + 15) >> 5;    // last k-tile with any unmasked entry
  for (int kt = 0; kt <= ktEnd; ++kt) {
    const int k0 = kt * 32;
#pragma unroll
    for (int hd = 0; hd < 2; ++hd) {   // ---- scores for this warp's heads ---
      const u16* Kb = Kg + ((size_t)(b * S_ + k0)) * D_ + (h0 + hd) * E_;
      bf16x8 kf[2][2];
#pragma unroll
      for (int nc = 0; nc < 2; ++nc)
#pragma unroll
        for (int c = 0; c < 2; ++c)
          kf[nc][c] = *(const bf16x8*)(Kb + (size_t)(nc * 16 + l16) * D_ +
                                       c * 32 + quad * 8);
      f32x4 sacc[2];
      sacc[0] = (f32x4){0.f, 0.f, 0.f, 0.f};
      sacc[1] = (f32x4){0.f, 0.f, 0.f, 0.f};
#pragma unroll
      for (int c = 0; c < 2; ++c)
#pragma unroll
        for (int nc = 0; nc < 2; ++nc)
          sacc[nc] = __builtin_amdgcn_mfma_f32_16x16x32_bf16(
              qf[hd][c], kf[nc][c], sacc[nc], 0, 0, 0);
#pragma unroll
      for (int nc = 0; nc < 2; ++nc)
#pragma unroll
        for (int reg = 0; reg < 4; ++reg) {
          int qrow = quad * 4 + reg;       // C: row=quad*4+reg
          int kcol = nc * 16 + l16;        // C: col=lane&15
          float s = sacc[nc][reg] * inv_rsq8;
          if ((k0 + kcol > q0 + qrow) || (s == 0.0f)) s = -1e9f;
          scf[h0 + hd][qrow][kcol] = s;
        }
    }
    __syncthreads();
    {  // ---- softmax across 16 heads at this thread's (q,k) ----
      const int qq = tid >> 5, kk = tid & 31;
      float v[16];
      float m = -3.0e38f;
#pragma unroll
      for (int hh = 0; hh < 16; ++hh) {
        v[hh] = scf[hh][qq][kk];
        m = fmaxf(m, v[hh]);
      }
      float sum = 0.f;
#pragma unroll
      for (int hh = 0; hh < 16; ++hh) {
        v[hh] = __expf(v[hh] - m);   // exp(0)=1, exp(-1e9)=0 exact
        sum += v[hh];
      }
      float inv = 1.0f / sum;        // all-masked: 1/16 (pow2) -> exact
#pragma unroll
      for (int hh = 0; hh < 16; ++hh) at[hh][qq][kk] = f2b(v[hh] * inv);
    }
    __syncthreads();
#pragma unroll
    for (int hd = 0; hd < 2; ++hd) {   // ---- O += attn @ V ----
      // A: m=q (lane&15), k=s (quad*8+j); 16B-aligned (row stride 80B)
      bf16x8 af = *(const bf16x8*)(&at[h0 + hd][l16][quad * 8]);
      const u16* Vb = Vt + ((size_t)((b * H_ + h0 + hd) * E_)) * S_ + k0;
#pragma unroll
      for (int nc = 0; nc < 4; ++nc) { // B: n=e (lane&15), k=s (quad*8+j)
        bf16x8 vf = *(const bf16x8*)(Vb + (size_t)(nc * 16 + l16) * S_ +
                                     quad * 8);
        oacc[hd][nc] = __builtin_amdgcn_mfma_f32_16x16x32_bf16(
            af, vf, oacc[hd][nc], 0, 0, 0);
      }
    }
    __syncthreads();
  }

  // ---- uniform tail: for k >= s0u ALL heads masked -> attn = 1/16 exactly.
  // out += (1/16) * sum_{s>=s0u} V[h][e][s]; fp32 reduction over Vt rows.
  float suf[2][4];
#pragma unroll
  for (int hd = 0; hd < 2; ++hd)
#pragma unroll
    for (int nc = 0; nc < 4; ++nc) suf[hd][nc] = 0.f;
  const int s0u = (ktEnd + 1) * 32;
  if (s0u < S_) {
    const int chunk = (S_ - s0u) >> 2;   // per-quad share, multiple of 8
#pragma unroll
    for (int hd = 0; hd < 2; ++hd)
#pragma unroll
      for (int nc = 0; nc < 4; ++nc) {
        const u16* vp = Vt +
            ((size_t)((b * H_ + h0 + hd) * E_ + nc * 16 + l16)) * S_ +
            s0u + quad * chunk;
        float a = 0.f;
        for (int s = 0; s < chunk; s += 8) {
          ushort8 v8 = *(const ushort8*)(vp + s);
#pragma unroll
          for (int j = 0; j < 8; ++j) a += b2f(v8[j]);
        }
        suf[hd][nc] = a;
      }
  }
#pragma unroll
  for (int hd = 0; hd < 2; ++hd)
#pragma unroll
    for (int nc = 0; nc < 4; ++nc) {
      float a = suf[hd][nc];
      a += __shfl_xor(a, 16);          // reduce across quad bits
      a += __shfl_xor(a, 32);
      suf[hd][nc] = a * 0.0625f;       // * 1/16 (exact)
    }

  // ---- output ----
#pragma unroll
  for (int hd = 0; hd < 2; ++hd) {
    u16* Ob = AO + ((size_t)(b * S_ + q0)) * D_ + (h0 + hd) * E_;
#pragma unroll
    for (int nc = 0; nc < 4; ++nc)
#pragma unroll
      for (int reg = 0; reg < 4; ++reg) {
        int qrow = quad * 4 + reg;
        int e    = nc * 16 + l16;
        Ob[(size_t)qrow * D_ + e] = f2b(oacc[hd][nc][reg] + suf[hd][nc]);
      }
  }
}

// ---------------------------------------------------------------------------
extern "C" void kernel_launch(void* const* d_in, const int* in_sizes, int n_in,
                              void* d_out, int out_size, void* d_ws,
                              size_t ws_size, hipStream_t stream)
{
  const float* X1 = (const float*)d_in[0];
  const float* X2 = (const float*)d_in[1];
  const float* Wq = (const float*)d_in[2];
  const float* bq = (const float*)d_in[3];
  const float* Wk = (const float*)d_in[4];
  const float* bk = (const float*)d_in[5];
  const float* Wv = (const float*)d_in[6];
  const float* bv = (const float*)d_in[7];
  const float* Wo = (const float*)d_in[8];
  const float* bo = (const float*)d_in[9];

  // Workspace (u16 units): X1b,X2b 8M; Wt 1M x4; Qb,Kb,Vb,Vtb 8M. AO aliases
  // Vb (dead after transpose_v). Total 44M u16 = 88MB.
  u16* X1b = (u16*)d_ws;
  u16* X2b = X1b + (8u << 20);
  u16* WtQ = X2b + (8u << 20);
  u16* WtK = WtQ + (1u << 20);
  u16* WtV = WtK + (1u << 20);
  u16* WtO = WtV + (1u << 20);
  u16* Qb  = WtO + (1u << 20);
  u16* Kb  = Qb + (8u << 20);
  u16* Vb  = Kb + (8u << 20);
  u16* Vtb = Vb + (8u << 20);
  u16* AOb = Vb;  // alias

  cvt_bf16<<<4096, 256, 0, stream>>>(X1, X1b);
  cvt_bf16<<<4096, 256, 0, stream>>>(X2, X2b);

  dim3 tg(16, 16);
  trans_cvt_w<<<tg, 256, 0, stream>>>(Wq, WtQ);
  trans_cvt_w<<<tg, 256, 0, stream>>>(Wk, WtK);
  trans_cvt_w<<<tg, 256, 0, stream>>>(Wv, WtV);
  trans_cvt_w<<<tg, 256, 0, stream>>>(Wo, WtO);

  dim3 gg(64, 8);  // (M/128, N/128)
  gemm_bf16<<<gg, 256, 0, stream>>>(X1b, WtQ, bq, Qb, 8192, 1024, 1024, 0);
  gemm_bf16<<<gg, 256, 0, stream>>>(X2b, WtK, bk, Kb, 8192, 1024, 1024, 0);
  gemm_bf16<<<gg, 256, 0, stream>>>(X2b, WtV, bv, Vb, 8192, 1024, 1024, 0);

  transpose_v<<<dim3(16, 128), 256, 0, stream>>>(Vb, Vtb);

  attn_headsoftmax<<<dim3(512), 512, 0, stream>>>(Qb, Kb, Vtb, AOb);

  // Output fp32 (reference returns float32).
  gemm_bf16<<<gg, 256, 0, stream>>>(AOb, WtO, bo, d_out, 8192, 1024, 1024, 1);
}

// Round 2
// 520.191 us; speedup vs baseline: 1.0194x; 1.0194x over previous
//
#include <hip/hip_runtime.h>
#include <cstdint>

// ---------------------------------------------------------------------------
// MultiHeadAttention (B=8,S=1024,D=1024,H=16,E=64). Inputs fp32, output fp32.
// Quirks: scale = 1/sqrt(8) (d_k = batch quirk); tril + exact-zero -> -1e9
// (fp32, pre-round); softmax over HEADS axis (local per (b,q,k)).
//
// R9: fix R8's regression.
//  (1) launch_bounds(512,4): VGPR cap 128 (R8's (512,6) forced VGPR=40 ->
//      scratch spills, WRITE_SIZE 16->43MB, per-iter remat).
//  (2) 2 barriers/iter: {softmax | bar | PV(t) + QK(t+1) | bar} — PV reads
//      `at`, next QK writes `scf` (disjoint), so the two MFMA phases merge
//      and K-loads hide under PV.
//  (3) cvt_bf16 kernels removed: GEMM gains fp32-A mode (reg-stage f2b ->
//      ds_write_b128; bit-identical to the old cvt+load path). -2 launches,
//      -64MB staging traffic.
//  Kept from R8: triangular skip (k>q => all heads masked => attn==1/16
//  exactly), uniform-suffix tail, long+short block pairing.
// ---------------------------------------------------------------------------

typedef unsigned short u16;
typedef unsigned int   u32;
typedef __attribute__((ext_vector_type(8))) __bf16         bf16x8;
typedef __attribute__((ext_vector_type(8))) unsigned short ushort8;
typedef __attribute__((ext_vector_type(4))) float          f32x4;

#define S_ 1024
#define D_ 1024
#define H_ 16
#define E_ 64

__device__ __forceinline__ float b2f(u16 h) {
  union { u32 u; float f; } v; v.u = ((u32)h) << 16; return v.f;
}
__device__ __forceinline__ u16 f2b(float f) {      // round-to-nearest-even
  union { float f; u32 u; } v; v.f = f;
  u32 r = v.u + 0x7fffu + ((v.u >> 16) & 1u);
  return (u16)(r >> 16);
}

typedef const __attribute__((address_space(1))) u32 gu32;
typedef       __attribute__((address_space(3))) u32 lu32;

// 16B global->LDS direct load; LDS dest must be wave-uniform base + lane*16.
__device__ __forceinline__ void gload_lds16(const u16* g, u16* l) {
  __builtin_amdgcn_global_load_lds((gu32*)(uintptr_t)g, (lu32*)(uintptr_t)l,
                                   16, 0, 0);
}

// ---------------------------------------------------------------------------
// Weight transpose+convert: W fp32 [K][N] -> Wt bf16 [N][K]. 64x64 tiles.
// ---------------------------------------------------------------------------
__global__ __launch_bounds__(256, 1) void trans_cvt_w(
    const float* __restrict__ W, u16* __restrict__ Wt)
{
  __shared__ u16 t[64][72];
  const int k0 = blockIdx.x * 64, n0 = blockIdx.y * 64;
  const int row = threadIdx.x >> 3;
  const int cs  = (threadIdx.x & 7) * 8;
#pragma unroll
  for (int p = 0; p < 2; ++p) {
    int r = row + p * 32;
    const float* Wp = W + (size_t)(k0 + r) * 1024 + n0 + cs;
    float4 a = *(const float4*)(Wp);
    float4 b = *(const float4*)(Wp + 4);
    u16* tp = &t[r][cs];
    tp[0] = f2b(a.x); tp[1] = f2b(a.y); tp[2] = f2b(a.z); tp[3] = f2b(a.w);
    tp[4] = f2b(b.x); tp[5] = f2b(b.y); tp[6] = f2b(b.z); tp[7] = f2b(b.w);
  }
  __syncthreads();
#pragma unroll
  for (int p = 0; p < 2; ++p) {
    int n = row + p * 32;
    ushort8 v;
#pragma unroll
    for (int i = 0; i < 8; ++i) v[i] = t[cs + i][n];
    *(ushort8*)(Wt + (size_t)(n0 + n) * 1024 + k0 + cs) = v;
  }
}

// ---------------------------------------------------------------------------
// bf16 MFMA GEMM: C[M][N] = A[M][K] @ Bt[N][K]^T + bias[N] (fp32 accum).
// 128x128 tile, BK=32, 256 threads / 4 waves. a_f32: A is fp32, staged via
// reg f2b (bit-identical to pre-converting); else bf16 via global_load_lds.
// out_f32: 1 -> fp32 stores, 0 -> bf16 stores.
// ---------------------------------------------------------------------------
__global__ __launch_bounds__(256, 1) void gemm_bf16(
    const void* __restrict__ A, const u16* __restrict__ Bt,
    const float* __restrict__ bias, void* __restrict__ Cv,
    int M, int N, int K, int out_f32, int a_f32)
{
  __shared__ u16 As[128 * 32];   // [m][k] row-major, 8KB
  __shared__ u16 Bs[128 * 32];   // [n][k] row-major, 8KB
  const int tid  = threadIdx.x;
  const int wave = tid >> 6;
  const int lane = tid & 63;
  const int quad = lane >> 4;
  const int l16  = lane & 15;
  const int m0   = (wave & 1) * 64;
  const int n0   = (wave >> 1) * 64;

  const u16*   Ab16 = (const u16*)A   + (size_t)blockIdx.x * 128 * K;
  const float* Abf  = (const float*)A + (size_t)blockIdx.x * 128 * K;
  const u16*   Bb   = Bt + (size_t)blockIdx.y * 128 * K;

  f32x4 acc[4][4];
#pragma unroll
  for (int i = 0; i < 4; ++i)
#pragma unroll
    for (int j = 0; j < 4; ++j) acc[i][j] = (f32x4){0.f, 0.f, 0.f, 0.f};

  for (int kb = 0; kb < K; kb += 32) {
    __syncthreads();               // prior iter's LDS reads done
    if (a_f32) {
#pragma unroll
      for (int p = 0; p < 2; ++p) {
        int seg = tid + p * 256;
        int row = seg >> 2, ks = seg & 3;
        const float* ap = Abf + (size_t)row * K + kb + ks * 8;
        float4 a = *(const float4*)(ap);
        float4 c = *(const float4*)(ap + 4);
        ushort8 o;
        o[0] = f2b(a.x); o[1] = f2b(a.y); o[2] = f2b(a.z); o[3] = f2b(a.w);
        o[4] = f2b(c.x); o[5] = f2b(c.y); o[6] = f2b(c.z); o[7] = f2b(c.w);
        *(ushort8*)(As + seg * 8) = o;
        gload_lds16(Bb + (size_t)row * K + kb + ks * 8, Bs + seg * 8);
      }
    } else {
#pragma unroll
      for (int p = 0; p < 2; ++p) {  // 512 16B segs over 256 threads
        int seg = tid + p * 256;     // = (wave*64+p*256) + lane -> base+lane*16
        int row = seg >> 2, ks = seg & 3;
        gload_lds16(Ab16 + (size_t)row * K + kb + ks * 8, As + seg * 8);
        gload_lds16(Bb   + (size_t)row * K + kb + ks * 8, Bs + seg * 8);
      }
    }
    __builtin_amdgcn_s_waitcnt(0); // drain vmcnt+lgkmcnt before barrier
    __syncthreads();

    bf16x8 af[4], bfr[4];
#pragma unroll
    for (int i = 0; i < 4; ++i)    // A-frag: m=lane&15, k=quad*8+j
      af[i] = *(const bf16x8*)(As + (m0 + i * 16 + l16) * 32 + quad * 8);
#pragma unroll
    for (int j = 0; j < 4; ++j)    // B-frag: n=lane&15, k=quad*8+j
      bfr[j] = *(const bf16x8*)(Bs + (n0 + j * 16 + l16) * 32 + quad * 8);
#pragma unroll
    for (int i = 0; i < 4; ++i)
#pragma unroll
      for (int j = 0; j < 4; ++j)
        acc[i][j] = __builtin_amdgcn_mfma_f32_16x16x32_bf16(
            af[i], bfr[j], acc[i][j], 0, 0, 0);
  }

  float bv[4];
#pragma unroll
  for (int j = 0; j < 4; ++j)
    bv[j] = bias[(size_t)blockIdx.y * 128 + n0 + j * 16 + l16];

  if (out_f32) {
    float* C = (float*)Cv;
#pragma unroll
    for (int i = 0; i < 4; ++i) {
      int r = blockIdx.x * 128 + m0 + i * 16 + quad * 4;   // row=quad*4+reg
#pragma unroll
      for (int j = 0; j < 4; ++j) {
        int c = blockIdx.y * 128 + n0 + j * 16 + l16;      // col=lane&15
#pragma unroll
        for (int reg = 0; reg < 4; ++reg)
          C[(size_t)(r + reg) * N + c] = acc[i][j][reg] + bv[j];
      }
    }
  } else {
    u16* C = (u16*)Cv;
#pragma unroll
    for (int i = 0; i < 4; ++i) {
      int r = blockIdx.x * 128 + m0 + i * 16 + quad * 4;
#pragma unroll
      for (int j = 0; j < 4; ++j) {
        int c = blockIdx.y * 128 + n0 + j * 16 + l16;
#pragma unroll
        for (int reg = 0; reg < 4; ++reg)
          C[(size_t)(r + reg) * N + c] = f2b(acc[i][j][reg] + bv[j]);
      }
    }
  }
}

// ---------------------------------------------------------------------------
// V transpose (bf16): V[b][s][h*64+e] -> Vt[(b*16+h)*64+e][s]  (per-head E,S)
// ---------------------------------------------------------------------------
__global__ __launch_bounds__(256, 1) void transpose_v(
    const u16* __restrict__ V, u16* __restrict__ Vt)
{
  __shared__ u16 t[64][72];
  const int s0 = blockIdx.x * 64;
  const int bh = blockIdx.y;           // b*16 + h
  const int b = bh >> 4, h = bh & 15;
  const int row = threadIdx.x >> 3;
  const int cs  = (threadIdx.x & 7) * 8;
#pragma unroll
  for (int p = 0; p < 2; ++p) {
    int s = row + p * 32;
    *(ushort8*)(&t[s][cs]) = *(const ushort8*)(
        V + ((size_t)(b * S_ + s0 + s)) * D_ + h * E_ + cs);
  }
  __syncthreads();
#pragma unroll
  for (int p = 0; p < 2; ++p) {
    int e = row + p * 32;
    ushort8 v;
#pragma unroll
    for (int i = 0; i < 8; ++i) v[i] = t[cs + i][e];
    *(ushort8*)(Vt + ((size_t)(bh * E_ + e)) * S_ + s0 + cs) = v;
  }
}

// ---------------------------------------------------------------------------
// Fused attention, softmax over HEADS, bf16 MFMA.
// R9: launch_bounds(512,4) (VGPR cap 128, no spills); 2-barrier iteration
// {softmax | bar | PV(t) + QK(t+1) | bar}; triangular skip + uniform tail;
// long+short block pairing; LDS 54.3KB -> 2 blocks/CU at grid 512.
// ---------------------------------------------------------------------------
__global__ __launch_bounds__(512, 4) void attn_headsoftmax(
    const u16* __restrict__ Qg,   // [B][S][D] bf16
    const u16* __restrict__ Kg,   // [B][S][D] bf16
    const u16* __restrict__ Vt,   // [B*H][E][S] bf16
    u16* __restrict__ AO)         // [B][S][D] bf16
{
  const int id   = blockIdx.x;         // 0..511
  const int b    = id & 7;
  const int x    = id >> 3;            // 0..63
  const int qt   = (x < 32) ? x : 95 - x;  // pair long+short per CU slot
  const int tid  = threadIdx.x;
  const int h0   = (tid >> 6) * 2;     // 2 heads per warp
  const int lane = tid & 63;
  const int quad = lane >> 4;
  const int l16  = lane & 15;
  const int q0   = qt * 16;

  __shared__ float scf[16][16][33];    // fp32 scores  (33.8 KB)
  __shared__ u16   at[16][16][40];     // bf16 attn    (20.5 KB)

  // Q fragments for both heads (row m = l16, k = quad*8+j over e-half c)
  bf16x8 qf[2][2];
#pragma unroll
  for (int hd = 0; hd < 2; ++hd) {
    const u16* Qb = Qg + ((size_t)(b * S_ + q0)) * D_ + (h0 + hd) * E_;
#pragma unroll
    for (int c = 0; c < 2; ++c)
      qf[hd][c] = *(const bf16x8*)(Qb + (size_t)l16 * D_ + c * 32 + quad * 8);
  }

  f32x4 oacc[2][4];
#pragma unroll
  for (int hd = 0; hd < 2; ++hd)
#pragma unroll
    for (int nc = 0; nc < 4; ++nc) oacc[hd][nc] = (f32x4){0.f, 0.f, 0.f, 0.f};

  // 1/sqrt(8), correctly rounded fp32; s==0 <=> dot==0 under both forms.
  const float inv_rsq8 = 0.35355339059327373f;

  const int ktEnd = (q0 + 15) >> 5;    // last k-tile with any unmasked entry

  // ---- QK^T phase: scores for this warp's 2 heads -> scf (fp32, masked)
  auto qk_phase = [&](int kt) {
    const int k0 = kt * 32;
#pragma unroll
    for (int hd = 0; hd < 2; ++hd) {
      const u16* Kb = Kg + ((size_t)(b * S_ + k0)) * D_ + (h0 + hd) * E_;
      bf16x8 kf[2][2];
#pragma unroll
      for (int nc = 0; nc < 2; ++nc)
#pragma unroll
        for (int c = 0; c < 2; ++c)
          kf[nc][c] = *(const bf16x8*)(Kb + (size_t)(nc * 16 + l16) * D_ +
                                       c * 32 + quad * 8);
      f32x4 sacc[2];
      sacc[0] = (f32x4){0.f, 0.f, 0.f, 0.f};
      sacc[1] = (f32x4){0.f, 0.f, 0.f, 0.f};
#pragma unroll
      for (int c = 0; c < 2; ++c)
#pragma unroll
        for (int nc = 0; nc < 2; ++nc)
          sacc[nc] = __builtin_amdgcn_mfma_f32_16x16x32_bf16(
              qf[hd][c], kf[nc][c], sacc[nc], 0, 0, 0);
#pragma unroll
      for (int nc = 0; nc < 2; ++nc)
#pragma unroll
        for (int reg = 0; reg < 4; ++reg) {
          int qrow = quad * 4 + reg;       // C: row=quad*4+reg
          int kcol = nc * 16 + l16;        // C: col=lane&15
          float s = sacc[nc][reg] * inv_rsq8;
          if ((k0 + kcol > q0 + qrow) || (s == 0.0f)) s = -1e9f;
          scf[h0 + hd][qrow][kcol] = s;
        }
    }
  };

  // ---- PV phase: O += attn @ V for this warp's 2 heads (reads `at`)
  auto pv_phase = [&](int kt) {
    const int k0 = kt * 32;
#pragma unroll
    for (int hd = 0; hd < 2; ++hd) {
      // A: m=q (lane&15), k=s (quad*8+j); 16B-aligned (row stride 80B)
      bf16x8 af = *(const bf16x8*)(&at[h0 + hd][l16][quad * 8]);
      const u16* Vb = Vt + ((size_t)((b * H_ + h0 + hd) * E_)) * S_ + k0;
#pragma unroll
      for (int nc = 0; nc < 4; ++nc) { // B: n=e (lane&15), k=s (quad*8+j)
        bf16x8 vf = *(const bf16x8*)(Vb + (size_t)(nc * 16 + l16) * S_ +
                                     quad * 8);
        oacc[hd][nc] = __builtin_amdgcn_mfma_f32_16x16x32_bf16(
            af, vf, oacc[hd][nc], 0, 0, 0);
      }
    }
  };

  qk_phase(0);
  __syncthreads();
  for (int kt = 0; kt <= ktEnd; ++kt) {
    {  // ---- softmax across 16 heads at this thread's (q,k): scf -> at ----
      const int qq = tid >> 5, kk = tid & 31;
      float v[16];
      float m = -3.0e38f;
#pragma unroll
      for (int hh = 0; hh < 16; ++hh) {
        v[hh] = scf[hh][qq][kk];
        m = fmaxf(m, v[hh]);
      }
      float sum = 0.f;
#pragma unroll
      for (int hh = 0; hh < 16; ++hh) {
        v[hh] = __expf(v[hh] - m);   // exp(0)=1, exp(-1e9)=0 exact
        sum += v[hh];
      }
      float inv = 1.0f / sum;        // all-masked: 1/16 (pow2) -> exact
#pragma unroll
      for (int hh = 0; hh < 16; ++hh) at[hh][qq][kk] = f2b(v[hh] * inv);
    }
    __syncthreads();
    // PV(t) reads `at`; QK(t+1) writes `scf` — disjoint buffers, one phase.
    pv_phase(kt);
    if (kt < ktEnd) qk_phase(kt + 1);
    __syncthreads();
  }

  // ---- uniform tail: for k >= s0u ALL heads masked -> attn = 1/16 exactly.
  // out += (1/16) * sum_{s>=s0u} V[h][e][s]; fp32 reduction over Vt rows.
  float suf[2][4];
#pragma unroll
  for (int hd = 0; hd < 2; ++hd)
#pragma unroll
    for (int nc = 0; nc < 4; ++nc) suf[hd][nc] = 0.f;
  const int s0u = (ktEnd + 1) * 32;
  if (s0u < S_) {
    const int chunk = (S_ - s0u) >> 2;   // per-quad share, multiple of 8
#pragma unroll
    for (int hd = 0; hd < 2; ++hd)
#pragma unroll
      for (int nc = 0; nc < 4; ++nc) {
        const u16* vp = Vt +
            ((size_t)((b * H_ + h0 + hd) * E_ + nc * 16 + l16)) * S_ +
            s0u + quad * chunk;
        float a = 0.f;
        for (int s = 0; s < chunk; s += 8) {
          ushort8 v8 = *(const ushort8*)(vp + s);
#pragma unroll
          for (int j = 0; j < 8; ++j) a += b2f(v8[j]);
        }
        suf[hd][nc] = a;
      }
  }
#pragma unroll
  for (int hd = 0; hd < 2; ++hd)
#pragma unroll
    for (int nc = 0; nc < 4; ++nc) {
      float a = suf[hd][nc];
      a += __shfl_xor(a, 16);          // reduce across quad bits
      a += __shfl_xor(a, 32);
      suf[hd][nc] = a * 0.0625f;       // * 1/16 (exact)
    }

  // ---- output ----
#pragma unroll
  for (int hd = 0; hd < 2; ++hd) {
    u16* Ob = AO + ((size_t)(b * S_ + q0)) * D_ + (h0 + hd) * E_;
#pragma unroll
    for (int nc = 0; nc < 4; ++nc)
#pragma unroll
      for (int reg = 0; reg < 4; ++reg) {
        int qrow = quad * 4 + reg;
        int e    = nc * 16 + l16;
        Ob[(size_t)qrow * D_ + e] = f2b(oacc[hd][nc][reg] + suf[hd][nc]);
      }
  }
}

// ---------------------------------------------------------------------------
extern "C" void kernel_launch(void* const* d_in, const int* in_sizes, int n_in,
                              void* d_out, int out_size, void* d_ws,
                              size_t ws_size, hipStream_t stream)
{
  const float* X1 = (const float*)d_in[0];
  const float* X2 = (const float*)d_in[1];
  const float* Wq = (const float*)d_in[2];
  const float* bq = (const float*)d_in[3];
  const float* Wk = (const float*)d_in[4];
  const float* bk = (const float*)d_in[5];
  const float* Wv = (const float*)d_in[6];
  const float* bv = (const float*)d_in[7];
  const float* Wo = (const float*)d_in[8];
  const float* bo = (const float*)d_in[9];

  // Workspace (u16 units): [X1b,X2b slots now unused — kept for layout
  // stability]; Wt 1M x4; Qb,Kb,Vb,Vtb 8M. AO aliases Vb (dead after
  // transpose_v). Total 44M u16 = 88MB.
  u16* X1b = (u16*)d_ws;
  u16* X2b = X1b + (8u << 20);
  u16* WtQ = X2b + (8u << 20);
  u16* WtK = WtQ + (1u << 20);
  u16* WtV = WtK + (1u << 20);
  u16* WtO = WtV + (1u << 20);
  u16* Qb  = WtO + (1u << 20);
  u16* Kb  = Qb + (8u << 20);
  u16* Vb  = Kb + (8u << 20);
  u16* Vtb = Vb + (8u << 20);
  u16* AOb = Vb;  // alias

  dim3 tg(16, 16);
  trans_cvt_w<<<tg, 256, 0, stream>>>(Wq, WtQ);
  trans_cvt_w<<<tg, 256, 0, stream>>>(Wk, WtK);
  trans_cvt_w<<<tg, 256, 0, stream>>>(Wv, WtV);
  trans_cvt_w<<<tg, 256, 0, stream>>>(Wo, WtO);

  dim3 gg(64, 8);  // (M/128, N/128)
  gemm_bf16<<<gg, 256, 0, stream>>>(X1, WtQ, bq, Qb, 8192, 1024, 1024, 0, 1);
  gemm_bf16<<<gg, 256, 0, stream>>>(X2, WtK, bk, Kb, 8192, 1024, 1024, 0, 1);
  gemm_bf16<<<gg, 256, 0, stream>>>(X2, WtV, bv, Vb, 8192, 1024, 1024, 0, 1);

  transpose_v<<<dim3(16, 128), 256, 0, stream>>>(Vb, Vtb);

  attn_headsoftmax<<<dim3(512), 512, 0, stream>>>(Qb, Kb, Vtb, AOb);

  // Output fp32 (reference returns float32).
  gemm_bf16<<<gg, 256, 0, stream>>>(AOb, WtO, bo, d_out, 8192, 1024, 1024, 1, 0);
}